// Round 5
// baseline (374.960 us; speedup 1.0000x reference)
//
#include <hip/hip_runtime.h>

#define NL 64
#define SQ 512
#define BATCH 1024

// DPP row_ror:<s> applied to v (old=0, full masks, bound_ctrl=1 -> foldable
// into the consuming VALU op by GCNDPPCombine).
template<int CTRL>
__device__ __forceinline__ float rotf(float v) {
    return __int_as_float(__builtin_amdgcn_update_dpp(
        0, __float_as_int(v), CTRL, 0xF, 0xF, true));
}

__device__ __forceinline__ float bperm(int addr, float v) {
    return __int_as_float(__builtin_amdgcn_ds_bpermute(addr, __float_as_int(v)));
}

__device__ __forceinline__ float lane0_bcast(float v) {
    return __uint_as_float(__builtin_amdgcn_readfirstlane(__float_as_uint(v)));
}

// stage (q,s): acc_q += row_ror<s>(c_q) * et[16q+s]
#define RSTG(q, s) acc##q = fmaf(rotf<0x120 + (s)>(c##q), et[16*(q) + (s)], acc##q)
#define QROW(q)                                                              \
    acc##q = fmaf(c##q, et[16*(q) + 0], acc##q);                             \
    RSTG(q, 1);  RSTG(q, 2);  RSTG(q, 3);  RSTG(q, 4);  RSTG(q, 5);          \
    RSTG(q, 6);  RSTG(q, 7);  RSTG(q, 8);  RSTG(q, 9);  RSTG(q, 10);         \
    RSTG(q, 11); RSTG(q, 12); RSTG(q, 13); RSTG(q, 14); RSTG(q, 15);

// One wave per batch row; lane j owns next-label j.
// Exp-domain recurrence p'_j = expE_j * sum_i p_i * ET[i][j], computed as a
// systolic all-to-all: 3 ds_bpermute make copies of p rotated by 16/32/48
// lanes; DPP row_ror:s (fused into v_fmac) covers the 16 in-row rotations.
// Every lane sees all 64 p_i with zero serial broadcast chain.
__global__ __launch_bounds__(64, 1) void crf_fwd(
    const float* __restrict__ emissions,   // [B, S, L]
    const int*   __restrict__ mask,        // [B, S]
    const float* __restrict__ trans,       // [L, L]  (prev, next)
    const float* __restrict__ start_t,     // [L]
    const float* __restrict__ end_t,       // [L]
    float* __restrict__ out)               // [B]
{
    const int b = blockIdx.x;
    const int j = threadIdx.x;             // next-label index

    const float* em = emissions + (size_t)b * SQ * NL;
    const int*   mk = mask + (size_t)b * SQ;

    // Runtime-resolve DPP row_ror direction (docs ambiguous; either works).
    const int pr  = __builtin_amdgcn_update_dpp(0, j, 0x121, 0xF, 0xF, true);
    const int d0  = __builtin_amdgcn_readfirstlane(pr);   // 1 or 15
    const int dir = (d0 == 1) ? 1 : -1;

    // et[16q+s] = exp(T[src][j]) where src is the prev-label whose p value
    // lane j receives at stage (q,s). Sweep covers all 64 exactly once.
    float et[NL];
#pragma unroll
    for (int q = 0; q < 4; ++q) {
#pragma unroll
        for (int s = 0; s < 16; ++s) {
            const int src = (j & 48) | ((j + dir * s) & 15);
            const int idx = (src + 16 * q) & 63;
            et[16 * q + s] = __expf(trans[idx * NL + j]);
        }
    }

    // bpermute addresses for 16/32/48-lane rotations (pull semantics)
    const int a1 = (((j + 16) & 63) << 2);
    const int a2 = (((j + 32) & 63) << 2);
    const int a3 = (((j + 48) & 63) << 2);

    float p, logC;
    {
        const float s0 = start_t[j] + em[j];   // t = 0
        const float C  = lane0_bcast(s0);
        p    = __expf(s0 - C);
        logC = C;
    }

    auto step = [&](float ex, int m) {
        const float c0 = p;
        const float c1 = bperm(a1, p);         // p[(l+16)&63]
        const float c2 = bperm(a2, p);         // p[(l+32)&63]
        const float c3 = bperm(a3, p);         // p[(l+48)&63]
        float acc0 = 0.f, acc1 = 0.f, acc2 = 0.f, acc3 = 0.f;
        QROW(0)                                // q=0 first: hides bpermute latency
        QROW(1)
        QROW(2)
        QROW(3)
        const float pn = ex * ((acc0 + acc1) + (acc2 + acc3));
        p = m ? pn : p;
    };

    // emission prefetch ring: slot(t) = (t-1)&7, loaded 8 steps ahead
    float r[8];
#pragma unroll
    for (int k = 0; k < 8; ++k) r[k] = em[(1 + k) * NL + j];

    for (int g = 0; g < 127; ++g) {
        const int t = 1 + 4 * g;               // steps t .. t+3
        const int s0 = (t - 1) & 7;

        const float ex0 = __expf(r[s0 + 0]);
        const float ex1 = __expf(r[s0 + 1]);
        const float ex2 = __expf(r[s0 + 2]);
        const float ex3 = __expf(r[s0 + 3]);

        // prefetch t+8 .. t+11 (clamped) into the slots just freed
#pragma unroll
        for (int k = 0; k < 4; ++k) {
            int tl = t + 8 + k; if (tl > SQ - 1) tl = SQ - 1;
            r[s0 + k] = em[tl * NL + j];
        }

        const int m0 = mk[t + 0];
        const int m1 = mk[t + 1];
        const int m2 = mk[t + 2];
        const int m3 = mk[t + 3];

        step(ex0, m0);
        step(ex1, m1);
        step(ex2, m2);
        step(ex3, m3);

        // renorm: keep p in fp32 range; invariant score_j = logC + log(p_j)
        const float r0 = lane0_bcast(p);
        logC += __logf(r0);
        p *= __builtin_amdgcn_rcpf(r0);
    }

    // tail: t = 509, 510, 511  (slots 4,5,6 hold them after g=125's prefetch)
    {
        const float ex0 = __expf(r[4]);
        const float ex1 = __expf(r[5]);
        const float ex2 = __expf(r[6]);
        step(ex0, mk[509]);
        step(ex1, mk[510]);
        step(ex2, mk[511]);
    }

    // out[b] = logC + log( sum_j p_j * exp(end_t[j]) )
    float v = p * __expf(end_t[j]);
#pragma unroll
    for (int off = 32; off; off >>= 1) v += __shfl_xor(v, off);
    if (j == 0) out[b] = logC + __logf(v);
}

extern "C" void kernel_launch(void* const* d_in, const int* in_sizes, int n_in,
                              void* d_out, int out_size, void* d_ws, size_t ws_size,
                              hipStream_t stream) {
    const float* emissions = (const float*)d_in[0];
    const int*   mask      = (const int*)d_in[1];
    const float* trans     = (const float*)d_in[2];
    const float* start_t   = (const float*)d_in[3];
    const float* end_t     = (const float*)d_in[4];
    float* out = (float*)d_out;

    crf_fwd<<<BATCH, NL, 0, stream>>>(emissions, mask, trans, start_t, end_t, out);
}

// Round 6
// 284.014 us; speedup vs baseline: 1.3202x; 1.3202x over previous
//
#include <hip/hip_runtime.h>

#define NL 64
#define SQ 512
#define BATCH 1024
#define TMID 256   // forward owns t=0..255, backward owns t=256..511

__device__ __forceinline__ float lane_bcast(float v, int lane) {
    return __uint_as_float(__builtin_amdgcn_readlane(__float_as_uint(v), lane));
}
__device__ __forceinline__ float lane0_bcast(float v) {
    return __uint_as_float(__builtin_amdgcn_readfirstlane(__float_as_uint(v)));
}

// Fwd/bwd split of the CRF scan: blocks 0..1023 run the forward exp-domain
// recurrence for t=1..255; blocks 1024..2047 run the backward recurrence for
// t=511..256. 2048 waves = 2/SIMD, so co-resident waves fill each other's
// serial-chain stalls (round 3 was 1 wave/SIMD, 38% stall).
//   fwd: p'_j = expE_j * sum_i p_i * ET[i][j]
//   bwd: q'_i = sum_j ET[i][j] * (expE_j * q_j)
// Partition: Z = sum_j p_255[j] * q_255[j]  (combine kernel).
__global__ __launch_bounds__(64, 2) void crf_scan(
    const float* __restrict__ emissions,   // [B, S, L]
    const int*   __restrict__ mask,        // [B, S]
    const float* __restrict__ trans,       // [L, L]
    const float* __restrict__ start_t,     // [L]
    const float* __restrict__ end_t,       // [L]
    float* __restrict__ ws_p,              // [2B][64]
    float* __restrict__ ws_c)              // [2B]
{
    const int  blk = blockIdx.x;
    const bool fwd = blk < BATCH;
    const int  b   = fwd ? blk : blk - BATCH;
    const int  j   = threadIdx.x;

    const float* em = emissions + (size_t)b * SQ * NL;
    const int*   mk = mask + (size_t)b * SQ;

    // fwd lane j needs column ET[:,j]; bwd lane i needs row ET[i,:].
    float et[NL];
    if (fwd) {
#pragma unroll
        for (int i = 0; i < NL; ++i) et[i] = __expf(trans[i * NL + j]);
    } else {
#pragma unroll
        for (int i = 0; i < NL; ++i) et[i] = __expf(trans[j * NL + i]);
    }

    auto matvec = [&](float y) {           // sum_i readlane(y,i) * et[i]
        float a0 = 0.f, a1 = 0.f, a2 = 0.f, a3 = 0.f;
#pragma unroll
        for (int i = 0; i < NL; i += 4) {
            a0 = fmaf(lane_bcast(y, i + 0), et[i + 0], a0);
            a1 = fmaf(lane_bcast(y, i + 1), et[i + 1], a1);
            a2 = fmaf(lane_bcast(y, i + 2), et[i + 2], a2);
            a3 = fmaf(lane_bcast(y, i + 3), et[i + 3], a3);
        }
        return (a0 + a1) + (a2 + a3);
    };

    float p, logC;

    if (fwd) {
        const float s0 = start_t[j] + em[j];       // t = 0
        const float C  = lane0_bcast(s0);
        p = __expf(s0 - C);  logC = C;

        float r0 = em[1 * NL + j], r1 = em[2 * NL + j];
        float r2 = em[3 * NL + j], r3 = em[4 * NL + j];

        for (int g = 0; g < 63; ++g) {             // steps t .. t+3, t = 1+4g
            const int t = 1 + 4 * g;
            const float e0 = __expf(r0), e1 = __expf(r1);
            const float e2 = __expf(r2), e3 = __expf(r3);
            int t7 = t + 7; if (t7 > TMID - 1) t7 = TMID - 1;
            r0 = em[(t + 4) * NL + j]; r1 = em[(t + 5) * NL + j];
            r2 = em[(t + 6) * NL + j]; r3 = em[t7 * NL + j];
            const int m0 = mk[t], m1 = mk[t + 1], m2 = mk[t + 2], m3 = mk[t + 3];
            { const float pn = e0 * matvec(p); p = m0 ? pn : p; }
            { const float pn = e1 * matvec(p); p = m1 ? pn : p; }
            { const float pn = e2 * matvec(p); p = m2 ? pn : p; }
            { const float pn = e3 * matvec(p); p = m3 ? pn : p; }
            const float c0 = lane0_bcast(p);       // renorm: range control
            logC += __logf(c0);
            p *= __builtin_amdgcn_rcpf(c0);
        }
        // tail t = 253, 254, 255
        const float e0 = __expf(r0), e1 = __expf(r1), e2 = __expf(r2);
        { const float pn = e0 * matvec(p); p = mk[253] ? pn : p; }
        { const float pn = e1 * matvec(p); p = mk[254] ? pn : p; }
        { const float pn = e2 * matvec(p); p = mk[255] ? pn : p; }
    } else {
        p = __expf(end_t[j]);  logC = 0.f;         // q_511 = exp(end)

        float r0 = em[511 * NL + j], r1 = em[510 * NL + j];
        float r2 = em[509 * NL + j], r3 = em[508 * NL + j];

        for (int g = 0; g < 64; ++g) {             // steps t, t-1, t-2, t-3
            const int t = 511 - 4 * g;
            const float e0 = __expf(r0), e1 = __expf(r1);
            const float e2 = __expf(r2), e3 = __expf(r3);
            int t4 = t - 4, t5 = t - 5, t6 = t - 6, t7 = t - 7;
            if (t4 < TMID) t4 = TMID;  if (t5 < TMID) t5 = TMID;
            if (t6 < TMID) t6 = TMID;  if (t7 < TMID) t7 = TMID;
            r0 = em[t4 * NL + j]; r1 = em[t5 * NL + j];
            r2 = em[t6 * NL + j]; r3 = em[t7 * NL + j];
            const int m0 = mk[t], m1 = mk[t - 1], m2 = mk[t - 2], m3 = mk[t - 3];
            { const float pn = matvec(e0 * p); p = m0 ? pn : p; }
            { const float pn = matvec(e1 * p); p = m1 ? pn : p; }
            { const float pn = matvec(e2 * p); p = m2 ? pn : p; }
            { const float pn = matvec(e3 * p); p = m3 ? pn : p; }
            const float c0 = lane0_bcast(p);
            logC += __logf(c0);
            p *= __builtin_amdgcn_rcpf(c0);
        }
    }

    ws_p[(size_t)blk * NL + j] = p;
    if (j == 0) ws_c[blk] = logC;
}

// out[b] = cf + cb + log( sum_j pf[j] * pb[j] )
__global__ __launch_bounds__(64) void crf_combine(
    const float* __restrict__ ws_p, const float* __restrict__ ws_c,
    float* __restrict__ out)
{
    const int b = blockIdx.x;
    const int j = threadIdx.x;
    float v = ws_p[(size_t)b * NL + j] * ws_p[(size_t)(b + BATCH) * NL + j];
#pragma unroll
    for (int off = 32; off; off >>= 1) v += __shfl_xor(v, off);
    if (j == 0) out[b] = ws_c[b] + ws_c[b + BATCH] + __logf(v);
}

extern "C" void kernel_launch(void* const* d_in, const int* in_sizes, int n_in,
                              void* d_out, int out_size, void* d_ws, size_t ws_size,
                              hipStream_t stream) {
    const float* emissions = (const float*)d_in[0];
    const int*   mask      = (const int*)d_in[1];
    const float* trans     = (const float*)d_in[2];
    const float* start_t   = (const float*)d_in[3];
    const float* end_t     = (const float*)d_in[4];
    float* out = (float*)d_out;

    float* ws_p = (float*)d_ws;                    // 2*1024*64 floats
    float* ws_c = ws_p + 2 * BATCH * NL;           // 2*1024 floats

    crf_scan<<<2 * BATCH, NL, 0, stream>>>(emissions, mask, trans,
                                           start_t, end_t, ws_p, ws_c);
    crf_combine<<<BATCH, NL, 0, stream>>>(ws_p, ws_c, out);
}

// Round 8
// 249.419 us; speedup vs baseline: 1.5033x; 1.1387x over previous
//
#include <hip/hip_runtime.h>

#define NL 64
#define SQ 512
#define BATCH 1024
#define TMID 256   // forward owns t=0..255, backward owns t=511..256

typedef __fp16 hf2 __attribute__((ext_vector_type(2)));

#define EXP2F(x)  __builtin_amdgcn_exp2f(x)   // 2^x (v_exp_f32)
#define LOG2F(x)  __builtin_amdgcn_logf(x)    // log2 (v_log_f32)

__device__ __forceinline__ float lane0_bcast(float v) {
    return __uint_as_float(__builtin_amdgcn_readfirstlane(__float_as_uint(v)));
}
__device__ __forceinline__ hf2 bc2(int pki, int lane) {
    int v = __builtin_amdgcn_readlane(pki, lane);
    return __builtin_bit_cast(hf2, v);
}

// Fwd/bwd split CRF scan (round-6 structure), core matvec halved via f16 dot2:
//   pack state pairs with DPP quad_perm(1,0,3,2) + cvt_pkrtz (even lane 2k
//   holds (x_2k, x_2k+1)); 32 readlane + 32 v_dot2_f32_f16 per step.
// Every-step renorm by 4*lane0(x) (tracked in log2-domain) keeps the f16
// operand window in [~5e-5, ~1.4e3]: spread of the state is bounded by
// per-step emission spread (+0.2 from transitions), ~e^8.5 for 64 N(0,1).
__global__ __launch_bounds__(64, 2) void crf_scan(
    const float* __restrict__ emissions,   // [B, S, L]
    const int*   __restrict__ mask,        // [B, S]
    const float* __restrict__ trans,       // [L, L]
    const float* __restrict__ start_t,     // [L]
    const float* __restrict__ end_t,       // [L]
    float* __restrict__ ws_p,              // [2B][64]
    float* __restrict__ ws_c)              // [2B]  (log2-domain offsets)
{
    const int  blk = blockIdx.x;
    const bool fwd = blk < BATCH;
    const int  b   = fwd ? blk : blk - BATCH;
    const int  j   = threadIdx.x;
    const float LOG2E = 1.44269504088896340736f;

    const float* em = emissions + (size_t)b * SQ * NL;
    const int*   mk = mask + (size_t)b * SQ;

    // ET as 32 packed f16 pairs: fwd lane j = column ET[:,j]; bwd lane i = row.
    hf2 et2[NL / 2];
#pragma unroll
    for (int k = 0; k < NL / 2; ++k) {
        float e0, e1;
        if (fwd) { e0 = __expf(trans[(2*k + 0) * NL + j]);
                   e1 = __expf(trans[(2*k + 1) * NL + j]); }
        else     { e0 = __expf(trans[j * NL + (2*k + 0)]);
                   e1 = __expf(trans[j * NL + (2*k + 1)]); }
        et2[k] = __builtin_amdgcn_cvt_pkrtz(e0, e1);
    }

    // sum_i x_i * et[i]  via packed-f16 dot2, broadcast from even lanes
    auto matvec = [&](float xb) -> float {
        int nb = __builtin_amdgcn_update_dpp(0, __float_as_int(xb),
                                             0xB1, 0xF, 0xF, true); // quad_perm(1,0,3,2)
        hf2 pk = __builtin_amdgcn_cvt_pkrtz(xb, __int_as_float(nb));
        int pki = __builtin_bit_cast(int, pk);
        float a0 = 0.f, a1 = 0.f, a2 = 0.f, a3 = 0.f;
#pragma unroll
        for (int k = 0; k < 32; k += 4) {
            a0 = __builtin_amdgcn_fdot2(bc2(pki, 2*(k+0)), et2[k+0], a0, false);
            a1 = __builtin_amdgcn_fdot2(bc2(pki, 2*(k+1)), et2[k+1], a1, false);
            a2 = __builtin_amdgcn_fdot2(bc2(pki, 2*(k+2)), et2[k+2], a2, false);
            a3 = __builtin_amdgcn_fdot2(bc2(pki, 2*(k+3)), et2[k+3], a3, false);
        }
        return (a0 + a1) + (a2 + a3);
    };

    float p, logC2;   // state (f32, renormed each step) + log2-domain offset

    if (fwd) {
        const float s0f = start_t[j] + em[j];          // t = 0
        const float C   = lane0_bcast(s0f);
        p = EXP2F((s0f - C) * LOG2E);  logC2 = C * LOG2E;

        auto step = [&](float r, int m) {
            const float ex   = EXP2F(r * LOG2E);       // e^emit
            const float p0   = lane0_bcast(p);
            const float sinv = 0.25f * __builtin_amdgcn_rcpf(p0);
            const float mv   = matvec(p * sinv);       // scaled state in f16
            if (m) { p = ex * mv; logC2 += LOG2F(p0) + 2.0f; }
        };

        float r0 = em[1*NL + j], r1 = em[2*NL + j];
        float r2 = em[3*NL + j], r3 = em[4*NL + j];

        for (int g = 0; g < 63; ++g) {                 // t = 1+4g .. +3
            const int t = 1 + 4 * g;
            const float e0 = r0, e1 = r1, e2 = r2, e3 = r3;
            int t7 = t + 7; if (t7 > TMID - 1) t7 = TMID - 1;
            r0 = em[(t+4)*NL + j]; r1 = em[(t+5)*NL + j];
            r2 = em[(t+6)*NL + j]; r3 = em[t7*NL + j];
            const int m0 = mk[t], m1 = mk[t+1], m2 = mk[t+2], m3 = mk[t+3];
            step(e0, m0); step(e1, m1); step(e2, m2); step(e3, m3);
        }
        step(r0, mk[253]); step(r1, mk[254]); step(r2, mk[255]);
    } else {
        p = __expf(end_t[j]);  logC2 = 0.f;            // q_511

        auto step = [&](float r, int m) {
            const float ex   = EXP2F(r * LOG2E);
            const float sc   = ex * p;                 // scale BEFORE matvec
            const float s0   = lane0_bcast(sc);
            const float sinv = 0.25f * __builtin_amdgcn_rcpf(s0);
            const float mv   = matvec(sc * sinv);
            if (m) { p = mv; logC2 += LOG2F(s0) + 2.0f; }
        };

        float r0 = em[511*NL + j], r1 = em[510*NL + j];
        float r2 = em[509*NL + j], r3 = em[508*NL + j];

        for (int g = 0; g < 64; ++g) {                 // t = 511-4g .. -3
            const int t = 511 - 4 * g;
            const float e0 = r0, e1 = r1, e2 = r2, e3 = r3;
            int t4 = t-4, t5 = t-5, t6 = t-6, t7 = t-7;
            if (t4 < TMID) t4 = TMID;  if (t5 < TMID) t5 = TMID;
            if (t6 < TMID) t6 = TMID;  if (t7 < TMID) t7 = TMID;
            r0 = em[t4*NL + j]; r1 = em[t5*NL + j];
            r2 = em[t6*NL + j]; r3 = em[t7*NL + j];
            const int m0 = mk[t], m1 = mk[t-1], m2 = mk[t-2], m3 = mk[t-3];
            step(e0, m0); step(e1, m1); step(e2, m2); step(e3, m3);
        }
    }

    ws_p[(size_t)blk * NL + j] = p;
    if (j == 0) ws_c[blk] = logC2;
}

// out[b] = ln2 * ( c2f + c2b + log2( sum_j pf[j] * pb[j] ) )
__global__ __launch_bounds__(64) void crf_combine(
    const float* __restrict__ ws_p, const float* __restrict__ ws_c,
    float* __restrict__ out)
{
    const int b = blockIdx.x;
    const int j = threadIdx.x;
    float v = ws_p[(size_t)b * NL + j] * ws_p[(size_t)(b + BATCH) * NL + j];
#pragma unroll
    for (int off = 32; off; off >>= 1) v += __shfl_xor(v, off);
    if (j == 0)
        out[b] = 0.69314718055994530942f *
                 (ws_c[b] + ws_c[b + BATCH] + LOG2F(v));
}

extern "C" void kernel_launch(void* const* d_in, const int* in_sizes, int n_in,
                              void* d_out, int out_size, void* d_ws, size_t ws_size,
                              hipStream_t stream) {
    const float* emissions = (const float*)d_in[0];
    const int*   mask      = (const int*)d_in[1];
    const float* trans     = (const float*)d_in[2];
    const float* start_t   = (const float*)d_in[3];
    const float* end_t     = (const float*)d_in[4];
    float* out = (float*)d_out;

    float* ws_p = (float*)d_ws;                    // 2*1024*64 floats
    float* ws_c = ws_p + 2 * BATCH * NL;           // 2*1024 floats

    crf_scan<<<2 * BATCH, NL, 0, stream>>>(emissions, mask, trans,
                                           start_t, end_t, ws_p, ws_c);
    crf_combine<<<BATCH, NL, 0, stream>>>(ws_p, ws_c, out);
}